// Round 4
// baseline (537.600 us; speedup 1.0000x reference)
//
#include <hip/hip_runtime.h>
#include <math.h>

// Problem constants: N=200 LSTMs, B=100, T=256, D=5 (io), H=20 (units)
constexpr int NL = 200;
constexpr int B  = 100;
constexpr int T  = 256;
constexpr int D  = 5;
constexpr int H  = 20;
constexpr int NG  = NL * B;                     // 20000 (lstm, batch) groups
constexpr int GPW = 3;                          // groups per wave (3*20=60 of 64 lanes)
constexpr int WPB = 4;                          // independent waves per block
constexpr int NWAVES = (NG + GPW - 1) / GPW;    // 6667
constexpr int NBLKS  = (NWAVES + WPB - 1) / WPB;// 1667

typedef float f2 __attribute__((ext_vector_type(2)));

__device__ __forceinline__ float rcpf(float x) { return __builtin_amdgcn_rcpf(x); }
__device__ __forceinline__ float sigm(float x) { return rcpf(1.0f + __expf(-x)); }
__device__ __forceinline__ float tanh_fast(float x) {
    return fmaf(-2.0f, rcpf(__expf(2.0f * x) + 1.0f), 1.0f);
}

// packed fma: z += {s,s} * a  (lowers to v_pk_fma_f32)
__device__ __forceinline__ f2 pkfma(float s, f2 a, f2 z) {
    f2 sv = {s, s};
    return __builtin_elementwise_fma(sv, a, z);
}

__global__ __launch_bounds__(256) void init_out_kernel(const float* __restrict__ dense_b,
                                                       float* __restrict__ out, int n) {
    int i = blockIdx.x * 256 + threadIdx.x;
    if (i < n) out[i] = dense_b[i % D];
}

// Wave-synchronous LSTM: wave owns 3 (n,b) groups of 20 lanes (lane = h).
// Weights in arch VGPRs as float2 gate-pairs (i,f) / (g,o); pinned in-loop so
// the register allocator cannot shuttle them through AGPRs. waves_per_eu(2,2)
// gives a 256-VGPR budget and disables the occupancy-raising heuristic.
// No barriers in the t-loop (wave-private LDS h exchange, in-order DS).
template<bool USE_WS>
__global__ __attribute__((amdgpu_flat_work_group_size(64 * WPB, 64 * WPB),
                          amdgpu_waves_per_eu(2, 2)))
void lstm_wave_kernel(
    const float* __restrict__ x,    // [B][T][D]
    const float* __restrict__ Wg,   // [N][D][4H]
    const float* __restrict__ Ug,   // [N][H][4H]
    const float* __restrict__ bg,   // [N][4H]
    const float* __restrict__ dWg,  // [N*H][D]
    float* __restrict__ pw,         // [N][T][B*D] partials (USE_WS)
    float* __restrict__ out)        // [B][T][D] (atomic fallback)
{
    const int tid  = threadIdx.x;
    const int wl   = tid >> 6;                   // wave within block
    const int lane = tid & 63;
    const long wav = (long)blockIdx.x * WPB + wl;

    const int grp = lane / 20;                   // 0..3 (grp 3 = 4 spare lanes)
    const bool gl = grp < 3;                     // gate lane?
    const int cg  = gl ? grp : 0;                // clamped group
    const int h   = lane % 20;

    long gid = wav * GPW + cg; if (gid > NG - 1) gid = NG - 1;
    const int n = (int)(gid / B), b = (int)(gid % B);

    // ---- dense role (lanes 0..59): item = (b',d'), kq = k-quarter ----
    const int item = lane >> 2;                  // 0..15
    const int kq   = lane & 3;
    const int it5  = (item < 15) ? item / 5 : 0;
    const int dd   = (item < 15) ? item % 5 : 0;
    long dgid = wav * GPW + it5; if (dgid > NG - 1) dgid = NG - 1;
    const int dn = (int)(dgid / B), db = (int)(dgid % B);
    float dwr[5];
    #pragma unroll
    for (int j = 0; j < 5; ++j) dwr[j] = dWg[(dn * H + kq * 5 + j) * D + dd];

    // ---- per-lane weight columns as (i,f)/(g,o) float2 pairs ----
    const float* up = Ug + (size_t)n * H * 4 * H + h;
    const float* wp = Wg + (size_t)n * D * 4 * H + h;
    const float* bp = bg + (size_t)n * 4 * H + h;
    f2 Uif[H], Ugo[H], Wif[D], Wgo[D];
    #pragma unroll
    for (int k = 0; k < H; ++k) {
        Uif[k] = (f2){up[k * 4 * H],         up[k * 4 * H + H]};
        Ugo[k] = (f2){up[k * 4 * H + 2 * H], up[k * 4 * H + 3 * H]};
    }
    #pragma unroll
    for (int d = 0; d < D; ++d) {
        Wif[d] = (f2){wp[d * 4 * H],         wp[d * 4 * H + H]};
        Wgo[d] = (f2){wp[d * 4 * H + 2 * H], wp[d * 4 * H + 3 * H]};
    }
    f2 bif = (f2){bp[0],     bp[H]};
    f2 bgo = (f2){bp[2 * H], bp[3 * H]};

#define PIN_U(A) asm("" : "+v"(A[0]),"+v"(A[1]),"+v"(A[2]),"+v"(A[3]),"+v"(A[4]), \
                         "+v"(A[5]),"+v"(A[6]),"+v"(A[7]),"+v"(A[8]),"+v"(A[9]), \
                         "+v"(A[10]),"+v"(A[11]),"+v"(A[12]),"+v"(A[13]),"+v"(A[14]), \
                         "+v"(A[15]),"+v"(A[16]),"+v"(A[17]),"+v"(A[18]),"+v"(A[19]))
#define PIN_W() asm("" : "+v"(Wif[0]),"+v"(Wif[1]),"+v"(Wif[2]),"+v"(Wif[3]),"+v"(Wif[4]), \
                        "+v"(Wgo[0]),"+v"(Wgo[1]),"+v"(Wgo[2]),"+v"(Wgo[3]),"+v"(Wgo[4]), \
                        "+v"(bif),"+v"(bgo))
    PIN_U(Uif); PIN_U(Ugo); PIN_W();

    // wave-private h double buffer (no cross-wave sharing -> no barriers)
    __shared__ __align__(16) float hbuf[WPB][2][GPW][H];
    if (lane < GPW * H) (&hbuf[wl][0][0][0])[lane] = 0.0f;   // h0 = 0
    __builtin_amdgcn_wave_barrier();

    const float* xq = x + (size_t)b * T * D;
    float* pwp = USE_WS ? (pw + ((size_t)dn * T) * (B * D) + db * D + dd)
                        : (out + (size_t)db * T * D + dd);

    float xr[D], xn[D];
    #pragma unroll
    for (int d = 0; d < D; ++d) xr[d] = xq[d];   // t = 0

    float c = 0.0f;
    int cur = 0;
    #pragma unroll 2
    for (int t = 0; t < T; ++t) {
        // prefetch x for t+1 (clamped); used next iteration
        const float* xnp = xq + ((t + 1 < T) ? D : 0);
        #pragma unroll
        for (int d = 0; d < D; ++d) xn[d] = xnp[d];

        f2 zif = bif, zgo = bgo;
        #pragma unroll
        for (int d = 0; d < D; ++d) {
            zif = pkfma(xr[d], Wif[d], zif);
            zgo = pkfma(xr[d], Wgo[d], zgo);
        }
        const float4* hr = (const float4*)&hbuf[wl][cur][cg][0];
        #pragma unroll
        for (int kk = 0; kk < H / 4; ++kk) {
            const float4 hv = hr[kk];
            zif = pkfma(hv.x, Uif[4*kk+0], zif); zgo = pkfma(hv.x, Ugo[4*kk+0], zgo);
            zif = pkfma(hv.y, Uif[4*kk+1], zif); zgo = pkfma(hv.y, Ugo[4*kk+1], zgo);
            zif = pkfma(hv.z, Uif[4*kk+2], zif); zgo = pkfma(hv.z, Ugo[4*kk+2], zgo);
            zif = pkfma(hv.w, Uif[4*kk+3], zif); zgo = pkfma(hv.w, Ugo[4*kk+3], zgo);
        }

        const float ig = sigm(zif.x);
        const float fg = sigm(zif.y);
        const float gg = tanh_fast(zgo.x);
        const float og = sigm(zgo.y);
        c = fmaf(fg, c, ig * gg);
        const float hv = og * tanh_fast(c);

        if (gl) hbuf[wl][cur ^ 1][grp][h] = hv;
        __builtin_amdgcn_wave_barrier();   // same-wave DS ops are in-order; fence compiler

        if (lane < 60) {
            const float* hd = &hbuf[wl][cur ^ 1][it5][kq * 5];
            float acc = hd[0] * dwr[0];
            #pragma unroll
            for (int j = 1; j < 5; ++j) acc = fmaf(hd[j], dwr[j], acc);
            acc += __shfl_xor(acc, 1);
            acc += __shfl_xor(acc, 2);
            if (kq == 0) {
                if (USE_WS) *pwp = acc;                 // private slot
                else        atomicAdd(pwp, acc);        // fallback
            }
        }
        #pragma unroll
        for (int d = 0; d < D; ++d) xr[d] = xn[d];
        xq  += D;
        pwp += USE_WS ? (B * D) : D;
        cur ^= 1;

        // keep weights resident in arch VGPRs across the loop (no AGPR shuttling)
        PIN_U(Uif); PIN_U(Ugo); PIN_W();
    }
#undef PIN_U
#undef PIN_W
}

// out[b][t][d] = dense_b[d] + sum_n pw[n][t][b*D+d]  (fully coalesced reads)
__global__ __launch_bounds__(512) void reduce_kernel(
    const float* __restrict__ pw, const float* __restrict__ dense_b,
    float* __restrict__ out)
{
    const int t    = blockIdx.x;
    const int flat = threadIdx.x;              // (b,d) flattened, 0..499
    if (flat >= B * D) return;
    float acc = dense_b[flat % D];
    const float* p = pw + (size_t)t * (B * D) + flat;
    constexpr size_t stride = (size_t)T * B * D;
    #pragma unroll 8
    for (int n = 0; n < NL; ++n) acc += p[n * stride];
    out[((size_t)(flat / D) * T + t) * D + flat % D] = acc;
}

extern "C" void kernel_launch(void* const* d_in, const int* in_sizes, int n_in,
                              void* d_out, int out_size, void* d_ws, size_t ws_size,
                              hipStream_t stream) {
    const float* x   = (const float*)d_in[0];
    const float* Wg  = (const float*)d_in[1];
    const float* Ug  = (const float*)d_in[2];
    const float* bg  = (const float*)d_in[3];
    const float* dWg = (const float*)d_in[4];
    const float* dbv = (const float*)d_in[5];
    float* out = (float*)d_out;

    const size_t need = (size_t)NL * T * B * D * sizeof(float);   // 102.4 MB
    if (ws_size >= need) {
        float* pw = (float*)d_ws;
        lstm_wave_kernel<true><<<NBLKS, 64 * WPB, 0, stream>>>(x, Wg, Ug, bg, dWg, pw, out);
        reduce_kernel<<<T, 512, 0, stream>>>(pw, dbv, out);
    } else {
        init_out_kernel<<<(out_size + 255) / 256, 256, 0, stream>>>(dbv, out, out_size);
        lstm_wave_kernel<false><<<NBLKS, 64 * WPB, 0, stream>>>(x, Wg, Ug, bg, dWg, nullptr, out);
    }
}

// Round 5
// 274.049 us; speedup vs baseline: 1.9617x; 1.9617x over previous
//
#include <hip/hip_runtime.h>
#include <math.h>

// Problem constants: N=200 LSTMs, B=100, T=256, D=5 (io), H=20 (units)
constexpr int NL = 200;
constexpr int B  = 100;
constexpr int T  = 256;
constexpr int D  = 5;
constexpr int H  = 20;
constexpr int NW = 7;      // waves (16-batch groups) per LSTM; 7*16=112 >= 100
constexpr int KP = 40;     // bcol row pitch in bf16 (80 B) — 2-way-max banks on writes

// k-axis layout of the per-batch data column (K=32):
//   k 0..19  = h_prev[0..19]
//   k 20..23 = 0 (set once)
//   k 24..28 = x_t[0..4]   (written per step as one aligned 16B store, k24..31)
//   k 29..31 = 0
constexpr int KX = 24;     // k index where x starts (byte offset 48: 16B aligned)

typedef float  f32x4  __attribute__((ext_vector_type(4)));
typedef short  bf16x8 __attribute__((ext_vector_type(8)));

__device__ __forceinline__ float rcpf(float x) { return __builtin_amdgcn_rcpf(x); }

#if __has_builtin(__builtin_amdgcn_exp2f)
__device__ __forceinline__ float exp2fast(float x) { return __builtin_amdgcn_exp2f(x); }
#else
__device__ __forceinline__ float exp2fast(float x) { return __expf(x * 0.6931471805599453f); }
#endif

// fp32 -> bf16 bits, round-to-nearest-even
__device__ __forceinline__ short f2bf(float f) {
    union { float f; unsigned u; } v; v.f = f;
    unsigned r = v.u + 0x7fffu + ((v.u >> 16) & 1u);
    return (short)(r >> 16);
}

constexpr float LOG2E  = 1.4426950408889634f;
constexpr float NLOG2E = -1.4426950408889634f;
constexpr float TLOG2E = 2.8853900817779268f;   // 2*log2(e)

__global__ __launch_bounds__(256) void init_out_kernel(const float* __restrict__ dense_b,
                                                       float* __restrict__ out, int n) {
    int i = blockIdx.x * 256 + threadIdx.x;
    if (i < n) out[i] = dense_b[i % D];
}

// One 64-thread block (one wave) per (lstm n, 16-batch group w).
// Transposed gate GEMM per timestep with v_mfma_f32_16x16x32_bf16:
//   A[80 x 32]  = gate weights, row r = 4*hh + gate, cols = k-layout above,
//                 rows pre-scaled by -log2e (i,f,o) / +2log2e (g)  [in registers]
//   Bmat[32 x 100] = per-batch data columns                        [LDS, bf16]
//   C[80 x 100] = gate pre-activations * scale; C-init = scaled bias (free)
// C/D layout (HW-verified): col = lane&15 (batch), row = (lane>>4)*4 + reg
//   => lane's 4 accs = {i,f,g,o} of (b = 16w+(lane&15), hh = 4*Mt + (lane>>4)).
// A/B k-order ambiguity is harmless: MFMA pairs A(lane,j) with B(lane,j)
// positionally per (k-group, j), and we build both with the same bijection
// k = 8*(lane>>4) + j.
template<bool USE_WS>
__global__ __attribute__((amdgpu_flat_work_group_size(64, 64),
                          amdgpu_waves_per_eu(2, 4)))
void lstm_mfma_kernel(
    const float* __restrict__ x,    // [B][T][D]
    const float* __restrict__ Wg,   // [N][D][4H]
    const float* __restrict__ Ug,   // [N][H][4H]
    const float* __restrict__ bg,   // [N][4H]
    const float* __restrict__ dWg,  // [N*H][D]
    float* __restrict__ pw,         // [N][T][B*D] partials (USE_WS)
    float* __restrict__ out)        // [B][T][D] (atomic fallback)
{
    const int blk = blockIdx.x;            // 0..1399
    const int n   = blk / NW;
    const int w   = blk % NW;
    const int l   = threadIdx.x;           // 0..63
    const int c16 = l & 15;
    const int g4  = l >> 4;                // k-group / row-group

    __shared__ __align__(16) short bcol[16][KP];   // [local batch][k], bf16 bits

    // zero-init (covers k20..23 and k29..31 permanently; h region for t=0)
    for (int i = l; i < 16 * KP / 2; i += 64) ((int*)bcol)[i] = 0;
    __builtin_amdgcn_wave_barrier();

    // ---- A fragments (gate weights), built once with k = 8*g4 + j ----
    const float* Un = Ug + (size_t)n * H * 4 * H;
    const float* Wn = Wg + (size_t)n * D * 4 * H;
    const float* bn = bg + (size_t)n * 4 * H;

    const int gateA = c16 & 3;                     // A-row gate for this lane
    const float sA  = (gateA == 2) ? TLOG2E : NLOG2E;
    bf16x8 afrag[5];
    #pragma unroll
    for (int Mt = 0; Mt < 5; ++Mt) {
        const int hhA = Mt * 4 + (c16 >> 2);       // A-row hh for this lane
        const int col = gateA * H + hhA;           // column in [*,4H] weight mats
        #pragma unroll
        for (int j = 0; j < 8; ++j) {
            const int k = 8 * g4 + j;
            float v = 0.0f;
            if (k < H)                     v = Un[k * 4 * H + col];
            else if (k >= KX && k < KX + D) v = Wn[(k - KX) * 4 * H + col];
            afrag[Mt][j] = f2bf(sA * v);
        }
    }

    // ---- C-init = scaled bias; cell state; dense weights (lane's hh set) ----
    const int hhC = g4;                            // within-tile: hh = 4*Mt + g4
    f32x4 biasv[5];
    float cst[5];
    float dwr[5][5];
    #pragma unroll
    for (int Mt = 0; Mt < 5; ++Mt) {
        const int hh = Mt * 4 + hhC;
        biasv[Mt][0] = NLOG2E * bn[0 * H + hh];
        biasv[Mt][1] = NLOG2E * bn[1 * H + hh];
        biasv[Mt][2] = TLOG2E * bn[2 * H + hh];
        biasv[Mt][3] = NLOG2E * bn[3 * H + hh];
        cst[Mt] = 0.0f;
        #pragma unroll
        for (int d = 0; d < D; ++d) dwr[Mt][d] = dWg[(n * H + hh) * D + d];
    }

    const int  bgl    = w * 16 + c16;              // global batch of this lane-col
    const bool bvalid = bgl < B;
    const float* xp   = x + (size_t)(bvalid ? bgl : 0) * T * D;
    float* pwp = USE_WS ? (pw + (size_t)n * T * (B * D) + (size_t)bgl * D)
                        : (out + ((size_t)bgl * T) * D);

    for (int t = 0; t < T; ++t) {
        // stage x_t into k24..31 of this lane's batch column (lanes 0..15)
        if (l < 16) {
            bf16x8 xb;
            #pragma unroll
            for (int d = 0; d < D; ++d) xb[d] = f2bf(xp[t * D + d]);
            xb[5] = 0; xb[6] = 0; xb[7] = 0;
            *(bf16x8*)&bcol[c16][KX] = xb;         // 16B aligned ds_write
        }
        __builtin_amdgcn_wave_barrier();           // order writes before read

        const bf16x8 bfrag = *(const bf16x8*)&bcol[c16][8 * g4];  // ds_read_b128

        f32x4 acc[5];
        #pragma unroll
        for (int Mt = 0; Mt < 5; ++Mt)
            acc[Mt] = __builtin_amdgcn_mfma_f32_16x16x32_bf16(afrag[Mt], bfrag,
                                                              biasv[Mt], 0, 0, 0);
        float hof[5];
        #pragma unroll
        for (int Mt = 0; Mt < 5; ++Mt) {
            // acc = {-z_i, -z_f, 2*z_g, -z_o} * log2e  (+scaled bias)
            const float iv = rcpf(1.0f + exp2fast(acc[Mt][0]));
            const float fv = rcpf(1.0f + exp2fast(acc[Mt][1]));
            const float gv = fmaf(-2.0f, rcpf(exp2fast(acc[Mt][2]) + 1.0f), 1.0f);
            const float ov = rcpf(1.0f + exp2fast(acc[Mt][3]));
            const float cv = fmaf(fv, cst[Mt], iv * gv);
            cst[Mt] = cv;
            const float th = fmaf(-2.0f, rcpf(exp2fast(TLOG2E * cv) + 1.0f), 1.0f);
            const float hv = ov * th;
            hof[Mt] = hv;
            bcol[c16][Mt * 4 + g4] = f2bf(hv);     // h for next step (k = hh)
        }

        // fused dense: out_part(b,d) = sum_hh h(b,hh) * dW[n*H+hh][d]
        // lane holds 5 hh's; reduce over the 4 row-groups with 2 shfl_xor.
        float sd[5];
        #pragma unroll
        for (int d = 0; d < D; ++d) {
            float s_ = hof[0] * dwr[0][d];
            #pragma unroll
            for (int Mt = 1; Mt < 5; ++Mt) s_ = fmaf(hof[Mt], dwr[Mt][d], s_);
            s_ += __shfl_xor(s_, 16);
            s_ += __shfl_xor(s_, 32);
            sd[d] = s_;
        }
        if (l < 16 && bvalid) {
            if (USE_WS) {
                #pragma unroll
                for (int d = 0; d < D; ++d) pwp[(size_t)t * (B * D) + d] = sd[d];
            } else {
                #pragma unroll
                for (int d = 0; d < D; ++d) atomicAdd(&pwp[(size_t)t * D + d], sd[d]);
            }
        }
    }
}

// out[b][t][d] = dense_b[d] + sum_n pw[n][t][b*D+d]  (coalesced reads)
__global__ __launch_bounds__(512) void reduce_kernel(
    const float* __restrict__ pw, const float* __restrict__ dense_b,
    float* __restrict__ out)
{
    const int t    = blockIdx.x;
    const int flat = threadIdx.x;              // (b,d) flattened, 0..499
    if (flat >= B * D) return;
    float acc = dense_b[flat % D];
    const float* p = pw + (size_t)t * (B * D) + flat;
    constexpr size_t stride = (size_t)T * B * D;
    #pragma unroll 8
    for (int n = 0; n < NL; ++n) acc += p[n * stride];
    out[((size_t)(flat / D) * T + t) * D + flat % D] = acc;
}

extern "C" void kernel_launch(void* const* d_in, const int* in_sizes, int n_in,
                              void* d_out, int out_size, void* d_ws, size_t ws_size,
                              hipStream_t stream) {
    const float* x   = (const float*)d_in[0];
    const float* Wg  = (const float*)d_in[1];
    const float* Ug  = (const float*)d_in[2];
    const float* bg  = (const float*)d_in[3];
    const float* dWg = (const float*)d_in[4];
    const float* dbv = (const float*)d_in[5];
    float* out = (float*)d_out;

    const size_t need = (size_t)NL * T * B * D * sizeof(float);   // 102.4 MB
    if (ws_size >= need) {
        float* pw = (float*)d_ws;
        lstm_mfma_kernel<true><<<NL * NW, 64, 0, stream>>>(x, Wg, Ug, bg, dWg, pw, out);
        reduce_kernel<<<T, 512, 0, stream>>>(pw, dbv, out);
    } else {
        init_out_kernel<<<(out_size + 255) / 256, 256, 0, stream>>>(dbv, out, out_size);
        lstm_mfma_kernel<false><<<NL * NW, 64, 0, stream>>>(x, Wg, Ug, bg, dWg, nullptr, out);
    }
}